// Round 3
// baseline (163.586 us; speedup 1.0000x reference)
//
#include <hip/hip_runtime.h>

// Fully-fused deformable-conv net, flat cell-parallel version.
// Global cell index = img*196 + (ph*14+pw); B*196 = 3136*256 exactly, so
// every lane of every wave is active (round 2 wasted wave 3: 196/256).
// A block's 256 cells span <=3 images; all 3 padded images staged in LDS.
// FC reduction: per-thread fc[10] -> LDS table -> 30-lane segmented serial
// sums -> one atomicAdd per (img,class). out is zero-init'd by memset;
// the cell==0 thread folds in b_fc.

#define WP 30
#define NPOS 784
#define NPOOL 1568
#define CELLS 196

__global__ __launch_bounds__(256) void deform_net_kernel(
    const float* __restrict__ x,       // (B,1,28,28)
    const float* __restrict__ w_off,   // (18,1,3,3)
    const float* __restrict__ b_off,   // (18,)
    const float* __restrict__ w_conv,  // (8,1,3,3)
    const float* __restrict__ w_fc,    // (10,1568)
    const float* __restrict__ b_fc,    // (10,)
    float* __restrict__ out,           // (B,10), pre-zeroed
    int B)
{
    __shared__ float xs[3][900];       // 3 padded images, 10.8 KB
    __shared__ float fc_s[256][10];    // per-thread FC partials, 10 KB

    const int tid      = threadIdx.x;
    const int cell0    = blockIdx.x << 8;      // first global cell of block
    const int img_base = cell0 / CELLS;        // uniform across block

    // Stage up to 3 zero-padded 30x30 images into LDS.
    for (int i = tid; i < 2700; i += 256) {
        int s = i / 900;
        int j = i - s * 900;
        int img = img_base + s;
        float v = 0.f;
        if (img < B) {
            int r = j / WP, c = j - r * WP;
            if (r >= 1 && r <= 28 && c >= 1 && c <= 28)
                v = x[(size_t)img * NPOS + (r - 1) * 28 + (c - 1)];
        }
        xs[s][j] = v;
    }
    __syncthreads();

    const int cg = cell0 + tid;
    float fc[10];
    #pragma unroll
    for (int c = 0; c < 10; c++) fc[c] = 0.f;

    if (cg < B * CELLS) {
        const int img  = cg / CELLS;
        const int cell = cg - img * CELLS;
        const int slot = img - img_base;
        const float* __restrict__ xsp = xs[slot];
        const int ph = cell / 14, pw = cell - ph * 14;  // pool cell coords
        const int h0 = 2 * ph, w0 = 2 * pw;

        // 4x4 padded-image neighborhood covering the 4 positions' 3x3 taps.
        float nb[16];
        #pragma unroll
        for (int i = 0; i < 4; i++)
            #pragma unroll
            for (int j = 0; j < 4; j++)
                nb[i * 4 + j] = xsp[(h0 + i) * WP + (w0 + j)];

        float hbf[4], wbf[4];
        #pragma unroll
        for (int i = 0; i < 4; i++) {
            hbf[i] = (float)(h0 + i);
            wbf[i] = (float)(w0 + i);
        }

        float acc[4][8];
        #pragma unroll
        for (int p = 0; p < 4; p++)
            #pragma unroll
            for (int o = 0; o < 8; o++) acc[p][o] = 0.f;

        #pragma unroll
        for (int k = 0; k < 9; k++) {          // deform tap
            const int kx = k / 3, ky = k % 3;
            #pragma unroll
            for (int p = 0; p < 4; p++) {      // position within pool cell
                const int dh = p >> 1, dw = p & 1;

                // offset channels k (x) and k+9 (y): 3x3 conv at this position
                float offx = b_off[k], offy = b_off[k + 9];
                #pragma unroll
                for (int t = 0; t < 9; t++) {
                    float nv = nb[(dh + t / 3) * 4 + (dw + t % 3)];
                    offx = fmaf(w_off[k * 9 + t],       nv, offx);
                    offy = fmaf(w_off[(k + 9) * 9 + t], nv, offy);
                }

                // sample point in padded frame: p = (h+kx, w+ky) + off
                float p_x = hbf[dh + kx] + offx;
                float p_y = wbf[dw + ky] + offy;

                float q0x = floorf(p_x), q0y = floorf(p_y);
                float qltx = fminf(fmaxf(q0x,       0.f), 29.f);
                float qlty = fminf(fmaxf(q0y,       0.f), 29.f);
                float qrbx = fminf(fmaxf(q0x + 1.f, 0.f), 29.f);
                float qrby = fminf(fmaxf(q0y + 1.f, 0.f), 29.f);
                float px   = fminf(fmaxf(p_x,       0.f), 29.f);
                float py   = fminf(fmaxf(p_y,       0.f), 29.f);

                float gltx = 1.f + (qltx - px);
                float glty = 1.f + (qlty - py);
                float grbx = 1.f - (qrbx - px);
                float grby = 1.f - (qrby - py);

                int ilx = (int)qltx, ily = (int)qlty;
                int irx = (int)qrbx, iry = (int)qrby;
                const float* row_l = xsp + ilx * WP;
                const float* row_r = xsp + irx * WP;

                // factored bilinear combine (6 VALU ops)
                float s = gltx * (glty * row_l[ily] + grby * row_l[iry])
                        + grbx * (glty * row_r[ily] + grby * row_r[iry]);

                #pragma unroll
                for (int o = 0; o < 8; o++)
                    acc[p][o] = fmaf(w_conv[o * 9 + k], s, acc[p][o]);
            }
        }

        // relu + 2x2 maxpool in registers
        float m[8];
        #pragma unroll
        for (int o = 0; o < 8; o++)
            m[o] = fmaxf(fmaxf(fmaxf(acc[0][o], acc[1][o]),
                               fmaxf(acc[2][o], acc[3][o])), 0.f);

        // FC partials: 10 base addresses, 8 imm-offset loads each (784 B)
        const float* wbase = w_fc + cell;
        #pragma unroll
        for (int c = 0; c < 10; c++) {
            const float* wr = wbase + c * NPOOL;
            #pragma unroll
            for (int o = 0; o < 8; o++)
                fc[c] = fmaf(m[o], wr[o * CELLS], fc[c]);
        }
        if (cell == 0) {
            #pragma unroll
            for (int c = 0; c < 10; c++) fc[c] += b_fc[c];
        }
    }

    #pragma unroll
    for (int c = 0; c < 10; c++) fc_s[tid][c] = fc[c];
    __syncthreads();

    // Segmented reduction: lane (s,c) of wave 0 sums image-slot s, class c.
    if (tid < 30) {
        int s = tid / 10, c = tid - s * 10;
        int img = img_base + s;
        if (img < B) {
            int lo = img * CELLS - cell0;       if (lo < 0)   lo = 0;
            int hi = (img + 1) * CELLS - cell0; if (hi > 256) hi = 256;
            int lim = B * CELLS - cell0;        if (hi > lim) hi = lim;
            if (lo < hi) {
                float a = 0.f;
                for (int t = lo; t < hi; t++) a += fc_s[t][c];
                atomicAdd(&out[img * 10 + c], a);
            }
        }
    }
}

extern "C" void kernel_launch(void* const* d_in, const int* in_sizes, int n_in,
                              void* d_out, int out_size, void* d_ws, size_t ws_size,
                              hipStream_t stream) {
    const float* x      = (const float*)d_in[0];
    const float* w_off  = (const float*)d_in[1];
    const float* b_off  = (const float*)d_in[2];
    const float* w_conv = (const float*)d_in[3];
    const float* w_fc   = (const float*)d_in[4];
    const float* b_fc   = (const float*)d_in[5];
    float* out = (float*)d_out;

    const int B = in_sizes[0] / NPOS;
    const int ncells = B * CELLS;
    const int grid = (ncells + 255) / 256;

    hipMemsetAsync(d_out, 0, (size_t)out_size * sizeof(float), stream);
    deform_net_kernel<<<grid, 256, 0, stream>>>(x, w_off, b_off, w_conv,
                                                w_fc, b_fc, out, B);
}

// Round 4
// 160.172 us; speedup vs baseline: 1.0213x; 1.0213x over previous
//
#include <hip/hip_runtime.h>

// Fully-fused deformable-conv net, flat cell-parallel, v2.
// Global cell index cg = img*196 + cell; B*196 = 3136*256 exactly -> every
// lane active. Block's 256 cells span <=3 images, staged padded in LDS.
// Fixes vs round 3:
//  - __launch_bounds__(256,4): 128-VGPR budget so nb[16]/acc[4][8] stay
//    register-resident (round 3's 40-VGPR schedule serialized the body).
//  - FC reduction: per-wave segmented butterfly (a wave spans <=2 images),
//    lane 0 atomicAdds straight to out. No 2nd barrier, no 10KB LDS table,
//    no serial wave-0 tail.

#define WP 30
#define NPOS 784
#define NPOOL 1568
#define CELLS 196

__global__ __launch_bounds__(256, 4) void deform_net_kernel(
    const float* __restrict__ x,       // (B,1,28,28)
    const float* __restrict__ w_off,   // (18,1,3,3)
    const float* __restrict__ b_off,   // (18,)
    const float* __restrict__ w_conv,  // (8,1,3,3)
    const float* __restrict__ w_fc,    // (10,1568)
    const float* __restrict__ b_fc,    // (10,)
    float* __restrict__ out,           // (B,10), pre-zeroed
    int B)
{
    __shared__ float xs[3][900];       // 3 padded images, 10.8 KB

    const int tid      = threadIdx.x;
    const int cell0    = blockIdx.x << 8;      // first global cell of block
    const int img_base = cell0 / CELLS;        // uniform across block

    // Stage up to 3 zero-padded 30x30 images into LDS.
    for (int i = tid; i < 2700; i += 256) {
        int s = i / 900;
        int j = i - s * 900;
        int img = img_base + s;
        float v = 0.f;
        if (img < B) {
            int r = j / WP, c = j - r * WP;
            if (r >= 1 && r <= 28 && c >= 1 && c <= 28)
                v = x[(size_t)img * NPOS + (r - 1) * 28 + (c - 1)];
        }
        xs[s][j] = v;
    }
    __syncthreads();

    const int cg  = cell0 + tid;
    const int img = cg / CELLS;                // image of this lane's cell
    float fc[10];
    #pragma unroll
    for (int c = 0; c < 10; c++) fc[c] = 0.f;

    if (cg < B * CELLS) {
        const int cell = cg - img * CELLS;
        const int slot = img - img_base;
        const float* __restrict__ xsp = xs[slot];
        const int ph = cell / 14, pw = cell - ph * 14;  // pool cell coords
        const int h0 = 2 * ph, w0 = 2 * pw;

        // 4x4 padded-image neighborhood covering the 4 positions' 3x3 taps.
        float nb[16];
        #pragma unroll
        for (int i = 0; i < 4; i++)
            #pragma unroll
            for (int j = 0; j < 4; j++)
                nb[i * 4 + j] = xsp[(h0 + i) * WP + (w0 + j)];

        float hbf[4], wbf[4];
        #pragma unroll
        for (int i = 0; i < 4; i++) {
            hbf[i] = (float)(h0 + i);
            wbf[i] = (float)(w0 + i);
        }

        float acc[4][8];
        #pragma unroll
        for (int p = 0; p < 4; p++)
            #pragma unroll
            for (int o = 0; o < 8; o++) acc[p][o] = 0.f;

        #pragma unroll
        for (int k = 0; k < 9; k++) {          // deform tap
            const int kx = k / 3, ky = k % 3;
            #pragma unroll
            for (int p = 0; p < 4; p++) {      // position within pool cell
                const int dh = p >> 1, dw = p & 1;

                // offset channels k (x) and k+9 (y): 3x3 conv at this position
                float offx = b_off[k], offy = b_off[k + 9];
                #pragma unroll
                for (int t = 0; t < 9; t++) {
                    float nv = nb[(dh + t / 3) * 4 + (dw + t % 3)];
                    offx = fmaf(w_off[k * 9 + t],       nv, offx);
                    offy = fmaf(w_off[(k + 9) * 9 + t], nv, offy);
                }

                // sample point in padded frame: p = (h+kx, w+ky) + off
                float p_x = hbf[dh + kx] + offx;
                float p_y = wbf[dw + ky] + offy;

                float q0x = floorf(p_x), q0y = floorf(p_y);
                float qltx = fminf(fmaxf(q0x,       0.f), 29.f);
                float qlty = fminf(fmaxf(q0y,       0.f), 29.f);
                float qrbx = fminf(fmaxf(q0x + 1.f, 0.f), 29.f);
                float qrby = fminf(fmaxf(q0y + 1.f, 0.f), 29.f);
                float px   = fminf(fmaxf(p_x,       0.f), 29.f);
                float py   = fminf(fmaxf(p_y,       0.f), 29.f);

                float gltx = 1.f + (qltx - px);
                float glty = 1.f + (qlty - py);
                float grbx = 1.f - (qrbx - px);
                float grby = 1.f - (qrby - py);

                int ilx = (int)qltx, ily = (int)qlty;
                int irx = (int)qrbx, iry = (int)qrby;
                const float* row_l = xsp + ilx * WP;
                const float* row_r = xsp + irx * WP;

                // factored bilinear combine
                float s = gltx * (glty * row_l[ily] + grby * row_l[iry])
                        + grbx * (glty * row_r[ily] + grby * row_r[iry]);

                #pragma unroll
                for (int o = 0; o < 8; o++)
                    acc[p][o] = fmaf(w_conv[o * 9 + k], s, acc[p][o]);
            }
        }

        // relu + 2x2 maxpool in registers
        float m[8];
        #pragma unroll
        for (int o = 0; o < 8; o++)
            m[o] = fmaxf(fmaxf(fmaxf(acc[0][o], acc[1][o]),
                               fmaxf(acc[2][o], acc[3][o])), 0.f);

        // FC partials: 10 base addresses, 8 imm-offset loads each
        const float* wbase = w_fc + cell;
        #pragma unroll
        for (int c = 0; c < 10; c++) {
            const float* wr = wbase + c * NPOOL;
            #pragma unroll
            for (int o = 0; o < 8; o++)
                fc[c] = fmaf(m[o], wr[o * CELLS], fc[c]);
        }
        if (cell == 0) {          // fold bias in exactly once per image
            #pragma unroll
            for (int c = 0; c < 10; c++) fc[c] += b_fc[c];
        }
    }

    // Per-wave segmented butterfly reduction. A 64-lane wave spans at most
    // 2 images (196 > 64). Wave-uniform branch picks the cheap path.
    const int lane = tid & 63;
    const int wave_first_cell = cell0 + (tid & ~63);
    const int seg0 = wave_first_cell / CELLS;
    const int seg1 = (wave_first_cell + 63) / CELLS;   // seg0 or seg0+1

    if (seg0 == seg1) {
        #pragma unroll
        for (int c = 0; c < 10; c++) {
            float v = fc[c];
            #pragma unroll
            for (int sh = 32; sh > 0; sh >>= 1) v += __shfl_down(v, sh, 64);
            if (lane == 0 && seg0 < B) atomicAdd(&out[seg0 * 10 + c], v);
        }
    } else {
        const bool in0 = (img == seg0);
        #pragma unroll
        for (int c = 0; c < 10; c++) {
            float v0 = in0 ? fc[c] : 0.f;
            float v1 = fc[c] - v0;
            #pragma unroll
            for (int sh = 32; sh > 0; sh >>= 1) {
                v0 += __shfl_down(v0, sh, 64);
                v1 += __shfl_down(v1, sh, 64);
            }
            if (lane == 0) {
                if (seg0 < B) atomicAdd(&out[seg0 * 10 + c], v0);
                if (seg1 < B) atomicAdd(&out[seg1 * 10 + c], v1);
            }
        }
    }
}

extern "C" void kernel_launch(void* const* d_in, const int* in_sizes, int n_in,
                              void* d_out, int out_size, void* d_ws, size_t ws_size,
                              hipStream_t stream) {
    const float* x      = (const float*)d_in[0];
    const float* w_off  = (const float*)d_in[1];
    const float* b_off  = (const float*)d_in[2];
    const float* w_conv = (const float*)d_in[3];
    const float* w_fc   = (const float*)d_in[4];
    const float* b_fc   = (const float*)d_in[5];
    float* out = (float*)d_out;

    const int B = in_sizes[0] / NPOS;
    const int ncells = B * CELLS;
    const int grid = (ncells + 255) / 256;

    hipMemsetAsync(d_out, 0, (size_t)out_size * sizeof(float), stream);
    deform_net_kernel<<<grid, 256, 0, stream>>>(x, w_off, b_off, w_conv,
                                                w_fc, b_fc, out, B);
}